// Round 3
// baseline (96.454 us; speedup 1.0000x reference)
//
#include <hip/hip_runtime.h>
#include <hip/hip_bf16.h>

// GMP: y[n] = sum_{k,l} a[k,l] x[n-l] |x[n-l]|^k
//          + sum_{k,l,m} b[k,l,m] x[n-l] |x[n-l-m]|^k
//          + sum_{k,l,m} c[k,l,m] x[n-l] |x[n-l+m]|^k
// Ka=5,La=4; Kb=4,Lb=3,Mb=4; Kc=4,Lc=3,Mc=4; indices clipped to [0,N-1].
// out: [2,N] fp32 (re then im).
//
// R2 = R1 with the macro->inline-function fix (braced init lists don't
// survive function-like macros). R1 changes vs R0:
//  - (re,im) packed into float2 ext-vectors -> v_pk_fma_f32 (157 TF path),
//    halving VALU instruction count in the Horner/cmac chains.
//  - LDS padding removed; r-array staged with halo -5 and x-arrays with
//    halo -3 so each thread's windows start at 16B-aligned 4*tid ->
//    7x ds_read_b128 per thread instead of 26x ds_read_b32.

typedef float v2f __attribute__((ext_vector_type(2)));

__device__ __forceinline__ v2f pkfma(v2f a, v2f b, v2f c) {
    return __builtin_elementwise_fma(a, b, c);
}

#define NTOT 1048576
#define BLOCK 256
#define EPT 4                        // elements per thread
#define TILE (BLOCK * EPT)           // 1024
// s_r[jr]  = |x[bs + jr - 5]|, jr in [0,1032): covers local -5 .. +1026
// s_x*[jx] =  x[bs + jx - 3],  jx in [0,1032): covers local -3 .. +1028
#define WIN 1032
#define STAGE_N 1034                 // staging loop: g = bs-5+j, j in [0,1034)

__global__ void __launch_bounds__(BLOCK) gmp_kernel(
    const float* __restrict__ x_re, const float* __restrict__ x_im,
    const float* __restrict__ a_re, const float* __restrict__ a_im,
    const float* __restrict__ b_re, const float* __restrict__ b_im,
    const float* __restrict__ c_re, const float* __restrict__ c_im,
    float* __restrict__ out)
{
    __shared__ __align__(16) float s_r[WIN];
    __shared__ __align__(16) float s_xr[WIN];
    __shared__ __align__(16) float s_xi[WIN];

    const int bs = blockIdx.x * TILE;

    // ---- stage tile + halo; one sqrt per staged element ----
    for (int j = threadIdx.x; j < STAGE_N; j += BLOCK) {
        int g = bs - 5 + j;
        g = max(g, 0);
        g = min(g, NTOT - 1);            // == jnp.clip semantics
        float xr = x_re[g];
        float xi = x_im[g];
        if (j < WIN) s_r[j] = sqrtf(fmaf(xr, xr, xi * xi));
        if (j >= 2) { s_xr[j - 2] = xr; s_xi[j - 2] = xi; }  // jx = j-2 < 1032
    }
    __syncthreads();

    // ---- per-thread register windows via ds_read_b128 ----
    const int t0 = threadIdx.x * EPT;    // multiple of 4 -> 16B aligned
    // element e needs r at n-d, d in [-3,5] -> rw[e+5-d]; jr = t0 + (e+5-d)
    float rw[12];
    *reinterpret_cast<float4*>(&rw[0]) = *reinterpret_cast<const float4*>(&s_r[t0]);
    *reinterpret_cast<float4*>(&rw[4]) = *reinterpret_cast<const float4*>(&s_r[t0 + 4]);
    *reinterpret_cast<float4*>(&rw[8]) = *reinterpret_cast<const float4*>(&s_r[t0 + 8]);
    // element e needs x at n-l, l in [0,3] -> xw[e+3-l]; jx = t0 + (e+3-l)
    float xwr[8], xwi[8];
    *reinterpret_cast<float4*>(&xwr[0]) = *reinterpret_cast<const float4*>(&s_xr[t0]);
    *reinterpret_cast<float4*>(&xwr[4]) = *reinterpret_cast<const float4*>(&s_xr[t0 + 4]);
    *reinterpret_cast<float4*>(&xwi[0]) = *reinterpret_cast<const float4*>(&s_xi[t0]);
    *reinterpret_cast<float4*>(&xwi[4]) = *reinterpret_cast<const float4*>(&s_xi[t0 + 4]);

    v2f acc[EPT];
#pragma unroll
    for (int e = 0; e < EPT; ++e) acc[e] = v2f{0.f, 0.f};

#pragma unroll
    for (int l = 0; l < 4; ++l) {
        // merged deg-4 complex poly in r[n-l]: a[k,l] (+ b[k,l,0] + c[k,l,0])
        v2f ca[5];
#pragma unroll
        for (int k = 0; k < 5; ++k)
            ca[k] = v2f{a_re[k * 4 + l], a_im[k * 4 + l]};
        if (l < 3) {
#pragma unroll
            for (int k = 0; k < 4; ++k) {
                int idx = (k * 3 + l) * 4;       // m = 0
                ca[k] += v2f{b_re[idx] + c_re[idx], b_im[idx] + c_im[idx]};
            }
        }

        v2f S[EPT];
#pragma unroll
        for (int e = 0; e < EPT; ++e) {
            float rv = rw[e + 5 - l];
            v2f rv2 = v2f{rv, rv};
            v2f s = ca[4];
            s = pkfma(s, rv2, ca[3]);
            s = pkfma(s, rv2, ca[2]);
            s = pkfma(s, rv2, ca[1]);
            s = pkfma(s, rv2, ca[0]);
            S[e] = s;
        }

        if (l < 3) {
#pragma unroll
            for (int m = 1; m < 4; ++m) {
                v2f cb[4], cc[4];
#pragma unroll
                for (int k = 0; k < 4; ++k) {
                    int idx = (k * 3 + l) * 4 + m;
                    cb[k] = v2f{b_re[idx], b_im[idx]};
                    cc[k] = v2f{c_re[idx], c_im[idx]};
                }
#pragma unroll
                for (int e = 0; e < EPT; ++e) {
                    float rb = rw[e + 5 - l - m];      // |x[n-l-m]|
                    v2f rb2 = v2f{rb, rb};
                    v2f sb = cb[3];
                    sb = pkfma(sb, rb2, cb[2]);
                    sb = pkfma(sb, rb2, cb[1]);
                    sb = pkfma(sb, rb2, cb[0]);
                    S[e] += sb;
                    float rc = rw[e + 5 - l + m];      // |x[n-l+m]|
                    v2f rc2 = v2f{rc, rc};
                    v2f sc = cc[3];
                    sc = pkfma(sc, rc2, cc[2]);
                    sc = pkfma(sc, rc2, cc[1]);
                    sc = pkfma(sc, rc2, cc[0]);
                    S[e] += sc;
                }
            }
        }

        // acc += x[n-l] * S  (complex, packed)
#pragma unroll
        for (int e = 0; e < EPT; ++e) {
            float xr = xwr[e + 3 - l], xi = xwi[e + 3 - l];
            v2f Ssw = v2f{S[e].y, S[e].x};
            v2f xr2 = v2f{xr, xr};
            v2f xi2 = v2f{-xi, xi};
            acc[e] = pkfma(xr2, S[e], acc[e]);
            acc[e] = pkfma(xi2, Ssw, acc[e]);
        }
    }

    // ---- coalesced float4 stores: out[0..N) = re, out[N..2N) = im ----
    const int n0 = bs + t0;              // multiple of 4 -> 16B aligned
    float4 vre = make_float4(acc[0].x, acc[1].x, acc[2].x, acc[3].x);
    float4 vim = make_float4(acc[0].y, acc[1].y, acc[2].y, acc[3].y);
    *reinterpret_cast<float4*>(out + n0) = vre;
    *reinterpret_cast<float4*>(out + NTOT + n0) = vim;
}

extern "C" void kernel_launch(void* const* d_in, const int* in_sizes, int n_in,
                              void* d_out, int out_size, void* d_ws, size_t ws_size,
                              hipStream_t stream)
{
    const float* x_re = (const float*)d_in[0];
    const float* x_im = (const float*)d_in[1];
    const float* a_re = (const float*)d_in[2];
    const float* a_im = (const float*)d_in[3];
    const float* b_re = (const float*)d_in[4];
    const float* b_im = (const float*)d_in[5];
    const float* c_re = (const float*)d_in[6];
    const float* c_im = (const float*)d_in[7];
    float* out = (float*)d_out;

    dim3 grid(NTOT / TILE);   // 1024 blocks, no tail
    gmp_kernel<<<grid, BLOCK, 0, stream>>>(x_re, x_im, a_re, a_im,
                                           b_re, b_im, c_re, c_im, out);
}